// Round 1
// baseline (232.581 us; speedup 1.0000x reference)
//
#include <hip/hip_runtime.h>

// Problem constants (fixed by the dataset)
constexpr int S_  = 4096;
constexpr int B_  = 2;
constexpr int C_  = 256;
constexpr int H_  = 8;
constexpr int E_  = 131072;
constexpr int CC_ = 32;
constexpr int MR  = S_ * B_;   // 8192 rows for all GEMMs

// ---------------- edge counting sort ----------------

__global__ void hist_kernel(const int* __restrict__ q_id, int* __restrict__ count) {
    int e = blockIdx.x * 256 + threadIdx.x;
    atomicAdd(&count[q_id[e]], 1);
}

__global__ __launch_bounds__(1024) void scan_kernel(const int* __restrict__ count,
                                                    int* __restrict__ base,
                                                    int* __restrict__ cursor) {
    __shared__ int sums[1024];
    int t = threadIdx.x;
    int c0 = count[4 * t + 0], c1 = count[4 * t + 1];
    int c2 = count[4 * t + 2], c3 = count[4 * t + 3];
    int tsum = c0 + c1 + c2 + c3;
    sums[t] = tsum;
    __syncthreads();
    for (int off = 1; off < 1024; off <<= 1) {
        int val = (t >= off) ? sums[t - off] : 0;
        __syncthreads();
        sums[t] += val;
        __syncthreads();
    }
    int excl = sums[t] - tsum;   // exclusive prefix of this thread's 4-chunk
    int b0 = excl, b1 = b0 + c0, b2 = b1 + c1, b3 = b2 + c2;
    base[4 * t + 0] = b0; base[4 * t + 1] = b1;
    base[4 * t + 2] = b2; base[4 * t + 3] = b3;
    cursor[4 * t + 0] = b0; cursor[4 * t + 1] = b1;
    cursor[4 * t + 2] = b2; cursor[4 * t + 3] = b3;
    if (t == 1023) base[S_] = b3 + c3;
}

__global__ void scatter_kernel(const int* __restrict__ q_id, const int* __restrict__ k_id,
                               int* __restrict__ cursor, int* __restrict__ kid_sorted) {
    int e = blockIdx.x * 256 + threadIdx.x;
    int pos = atomicAdd(&cursor[q_id[e]], 1);
    kid_sorted[pos] = k_id[e];
}

// ---------------- fp32 tiled GEMM:  Out[M,N] = A[M,K] @ W[N,K]^T + bias ----------------
// BM=BN=64, BK=32, 256 threads, 4x4 per thread.

__device__ __forceinline__ void gemm_body(const float* __restrict__ A,
                                          const float* __restrict__ W,
                                          const float* __restrict__ bias,
                                          float* __restrict__ Out,
                                          int bm, int bn) {
    constexpr int K = C_;
    constexpr int N = C_;
    __shared__ __align__(16) float As[32][68];   // [k][m], padded stride 68 (272B, 16B-mult)
    __shared__ __align__(16) float Bs[32][68];   // [k][n]
    const int tid = threadIdx.x;
    const int tx = tid & 15, ty = tid >> 4;
    float acc[4][4] = {};
    for (int k0 = 0; k0 < K; k0 += 32) {
#pragma unroll
        for (int i = 0; i < 2; ++i) {
            int l  = i * 256 + tid;      // 0..511  (512 float4 per tile)
            int r  = l >> 3;             // row 0..63
            int kq = (l & 7) << 2;       // k offset 0,4,...,28
            float4 av = *(const float4*)&A[(bm + r) * K + k0 + kq];
            As[kq + 0][r] = av.x; As[kq + 1][r] = av.y;
            As[kq + 2][r] = av.z; As[kq + 3][r] = av.w;
            float4 wv = *(const float4*)&W[(bn + r) * K + k0 + kq];
            Bs[kq + 0][r] = wv.x; Bs[kq + 1][r] = wv.y;
            Bs[kq + 2][r] = wv.z; Bs[kq + 3][r] = wv.w;
        }
        __syncthreads();
#pragma unroll
        for (int kk = 0; kk < 32; ++kk) {
            float4 a4 = *(const float4*)&As[kk][ty << 2];
            float4 b4 = *(const float4*)&Bs[kk][tx << 2];
            float a[4] = {a4.x, a4.y, a4.z, a4.w};
            float b[4] = {b4.x, b4.y, b4.z, b4.w};
#pragma unroll
            for (int i = 0; i < 4; ++i)
#pragma unroll
                for (int j = 0; j < 4; ++j)
                    acc[i][j] = fmaf(a[i], b[j], acc[i][j]);
        }
        __syncthreads();
    }
    float4 bias4 = *(const float4*)&bias[bn + (tx << 2)];
    float bb[4] = {bias4.x, bias4.y, bias4.z, bias4.w};
#pragma unroll
    for (int i = 0; i < 4; ++i) {
        int row = bm + (ty << 2) + i;
        float4 o;
        o.x = acc[i][0] + bb[0];
        o.y = acc[i][1] + bb[1];
        o.z = acc[i][2] + bb[2];
        o.w = acc[i][3] + bb[3];
        *(float4*)&Out[row * N + bn + (tx << 2)] = o;
    }
}

__global__ __launch_bounds__(256) void gemm_qkv(const float* __restrict__ x,
        const float* __restrict__ Wq, const float* __restrict__ bq,
        const float* __restrict__ Wk, const float* __restrict__ bk,
        const float* __restrict__ Wv, const float* __restrict__ bv,
        float* __restrict__ q, float* __restrict__ k, float* __restrict__ v) {
    int z = blockIdx.z;
    const float* W    = (z == 0) ? Wq : (z == 1) ? Wk : Wv;
    const float* bias = (z == 0) ? bq : (z == 1) ? bk : bv;
    float* Out        = (z == 0) ? q  : (z == 1) ? k  : v;
    gemm_body(x, W, bias, Out, blockIdx.x * 64, blockIdx.y * 64);
}

__global__ __launch_bounds__(256) void gemm_out(const float* __restrict__ A,
        const float* __restrict__ W, const float* __restrict__ bias,
        float* __restrict__ Out) {
    gemm_body(A, W, bias, Out, blockIdx.x * 64, blockIdx.y * 64);
}

// ---------------- edge attention: one wave per (s,b) row ----------------
// lane holds 4 channels (float4); head = lane>>3; dot reduce over 8 lanes.

__global__ __launch_bounds__(256) void attn_edge(
        const float* __restrict__ q, const float* __restrict__ k, const float* __restrict__ v,
        const int* __restrict__ base, const int* __restrict__ kid,
        float* __restrict__ attn) {
    const int lane = threadIdx.x & 63;
    const int wave = threadIdx.x >> 6;
    const int sb = blockIdx.x * 4 + wave;   // 0..MR-1
    const int s = sb >> 1;                  // B_ == 2
    const int b = sb & 1;
    const int e0 = __builtin_amdgcn_readfirstlane(base[s]);
    const int e1 = __builtin_amdgcn_readfirstlane(base[s + 1]);
    const int col = lane << 2;              // channel group start within 256
    const float4 q4 = *(const float4*)&q[sb * C_ + col];
    float4 acc = {0.f, 0.f, 0.f, 0.f};
    float wsum = 0.f;
    const float scale = 0.17677669529663687f;   // 1/sqrt(CC)
    for (int j = e0; j < e1; ++j) {
        const int ke = kid[j];
        const int krow = (ke * B_ + b) * C_ + col;
        const float4 k4 = *(const float4*)&k[krow];
        const float4 v4 = *(const float4*)&v[krow];
        float p = q4.x * k4.x + q4.y * k4.y + q4.z * k4.z + q4.w * k4.w;
        p += __shfl_xor(p, 1);
        p += __shfl_xor(p, 2);
        p += __shfl_xor(p, 4);
        const float w = __expf(p * scale);
        acc.x = fmaf(w, v4.x, acc.x);
        acc.y = fmaf(w, v4.y, acc.y);
        acc.z = fmaf(w, v4.z, acc.z);
        acc.w = fmaf(w, v4.w, acc.w);
        wsum += w;
    }
    const float inv = 1.0f / wsum;
    float4 o;
    o.x = acc.x * inv; o.y = acc.y * inv; o.z = acc.z * inv; o.w = acc.w * inv;
    *(float4*)&attn[sb * C_ + col] = o;
}

// ---------------- launch ----------------

extern "C" void kernel_launch(void* const* d_in, const int* in_sizes, int n_in,
                              void* d_out, int out_size, void* d_ws, size_t ws_size,
                              hipStream_t stream) {
    const float* x  = (const float*)d_in[0];
    const int* q_id = (const int*)d_in[1];
    const int* k_id = (const int*)d_in[2];
    const float* Wq = (const float*)d_in[3];
    const float* bq = (const float*)d_in[4];
    const float* Wk = (const float*)d_in[5];
    const float* bk = (const float*)d_in[6];
    const float* Wv = (const float*)d_in[7];
    const float* bv = (const float*)d_in[8];
    const float* Wx = (const float*)d_in[9];
    const float* bx = (const float*)d_in[10];
    float* out = (float*)d_out;

    float* wsf  = (float*)d_ws;
    float* q    = wsf;
    float* k    = q + (size_t)MR * C_;
    float* v    = k + (size_t)MR * C_;
    float* attn = v + (size_t)MR * C_;
    int* wsi        = (int*)(attn + (size_t)MR * C_);
    int* count      = wsi;
    int* base       = count + S_;
    int* cursor     = base + S_ + 1;
    int* kid_sorted = cursor + S_;

    hipMemsetAsync(count, 0, S_ * sizeof(int), stream);
    hist_kernel<<<E_ / 256, 256, 0, stream>>>(q_id, count);
    scan_kernel<<<1, 1024, 0, stream>>>(count, base, cursor);
    scatter_kernel<<<E_ / 256, 256, 0, stream>>>(q_id, k_id, cursor, kid_sorted);

    gemm_qkv<<<dim3(MR / 64, C_ / 64, 3), 256, 0, stream>>>(
        x, Wq, bq, Wk, bk, Wv, bv, q, k, v);

    attn_edge<<<MR / 4, 256, 0, stream>>>(q, k, v, base, kid_sorted, attn);

    gemm_out<<<dim3(MR / 64, C_ / 64), 256, 0, stream>>>(attn, Wx, bx, out);
}

// Round 2
// 163.118 us; speedup vs baseline: 1.4258x; 1.4258x over previous
//
#include <hip/hip_runtime.h>

// Problem constants (fixed by the dataset)
constexpr int S_  = 4096;
constexpr int B_  = 2;
constexpr int C_  = 256;
constexpr int H_  = 8;
constexpr int E_  = 131072;
constexpr int CC_ = 32;
constexpr int MR  = S_ * B_;   // 8192 rows for all GEMMs

typedef __attribute__((ext_vector_type(8))) short bf16x8_t;
typedef __attribute__((ext_vector_type(4))) float f32x4_t;

__device__ __forceinline__ unsigned short f2bf(float f) {
    unsigned int u = __float_as_uint(f);
    u += 0x7fffu + ((u >> 16) & 1u);   // round-to-nearest-even
    return (unsigned short)(u >> 16);
}
__device__ __forceinline__ float bflo(unsigned int u) { return __uint_as_float(u << 16); }
__device__ __forceinline__ float bfhi(unsigned int u) { return __uint_as_float(u & 0xffff0000u); }

// ---------------- edge counting sort ----------------

__global__ void hist_kernel(const int* __restrict__ q_id, int* __restrict__ count) {
    int e = blockIdx.x * 256 + threadIdx.x;
    atomicAdd(&count[q_id[e]], 1);
}

__global__ __launch_bounds__(1024) void scan_kernel(const int* __restrict__ count,
                                                    int* __restrict__ base,
                                                    int* __restrict__ cursor) {
    __shared__ int sums[1024];
    int t = threadIdx.x;
    int c0 = count[4 * t + 0], c1 = count[4 * t + 1];
    int c2 = count[4 * t + 2], c3 = count[4 * t + 3];
    int tsum = c0 + c1 + c2 + c3;
    sums[t] = tsum;
    __syncthreads();
    for (int off = 1; off < 1024; off <<= 1) {
        int val = (t >= off) ? sums[t - off] : 0;
        __syncthreads();
        sums[t] += val;
        __syncthreads();
    }
    int excl = sums[t] - tsum;
    int b0 = excl, b1 = b0 + c0, b2 = b1 + c1, b3 = b2 + c2;
    base[4 * t + 0] = b0; base[4 * t + 1] = b1;
    base[4 * t + 2] = b2; base[4 * t + 3] = b3;
    cursor[4 * t + 0] = b0; cursor[4 * t + 1] = b1;
    cursor[4 * t + 2] = b2; cursor[4 * t + 3] = b3;
    if (t == 1023) base[S_] = b3 + c3;
}

__global__ void scatter_kernel(const int* __restrict__ q_id, const int* __restrict__ k_id,
                               int* __restrict__ cursor, int* __restrict__ kid_sorted) {
    int e = blockIdx.x * 256 + threadIdx.x;
    int pos = atomicAdd(&cursor[q_id[e]], 1);
    kid_sorted[pos] = k_id[e];
}

// ---------------- fp32 -> bf16 casts ----------------

__global__ void cast_x_kernel(const float* __restrict__ src, unsigned short* __restrict__ dst) {
    int i = blockIdx.x * 256 + threadIdx.x;     // one thread = 8 elements
    const float4* s = (const float4*)src + (size_t)i * 2;
    float4 a = s[0], b = s[1];
    uint4 o;
    o.x = (unsigned)f2bf(a.x) | ((unsigned)f2bf(a.y) << 16);
    o.y = (unsigned)f2bf(a.z) | ((unsigned)f2bf(a.w) << 16);
    o.z = (unsigned)f2bf(b.x) | ((unsigned)f2bf(b.y) << 16);
    o.w = (unsigned)f2bf(b.z) | ((unsigned)f2bf(b.w) << 16);
    *((uint4*)dst + i) = o;
}

__global__ void cast_w4_kernel(const float* __restrict__ Wq, const float* __restrict__ Wk,
                               const float* __restrict__ Wv, const float* __restrict__ Wx,
                               unsigned short* __restrict__ dst) {
    int z = blockIdx.z;
    const float* src = (z == 0) ? Wq : (z == 1) ? Wk : (z == 2) ? Wv : Wx;
    unsigned short* d = dst + (size_t)z * (C_ * C_);
    int i = blockIdx.x * 256 + threadIdx.x;     // 8192 threads per matrix, 8 elems each
    const float4* s = (const float4*)src + (size_t)i * 2;
    float4 a = s[0], b = s[1];
    uint4 o;
    o.x = (unsigned)f2bf(a.x) | ((unsigned)f2bf(a.y) << 16);
    o.y = (unsigned)f2bf(a.z) | ((unsigned)f2bf(a.w) << 16);
    o.z = (unsigned)f2bf(b.x) | ((unsigned)f2bf(b.y) << 16);
    o.w = (unsigned)f2bf(b.z) | ((unsigned)f2bf(b.w) << 16);
    *((uint4*)d + i) = o;
}

// ---------------- bf16 MFMA GEMM: Out[M,N] = A[M,K] @ W[N,K]^T + bias ----------------
// 128x128 tile, BK=64, 256 threads (4 waves, 2x2), 4x4 16x16x32 mfma tiles per wave.

__device__ __forceinline__ void gemm_mfma_body(
        const unsigned short* __restrict__ A, const unsigned short* __restrict__ W,
        const float* __restrict__ bias,
        unsigned short* __restrict__ outb, float* __restrict__ outf,
        int ostride, int ooff, int bm, int bn) {
    __shared__ __align__(16) unsigned short As[128][72];   // +8 pad: 144B row stride
    __shared__ __align__(16) unsigned short Bs[128][72];
    const int tid = threadIdx.x;
    const int lane = tid & 63, wave = tid >> 6;
    const int wm = wave >> 1, wn = wave & 1;
    const int l16 = lane & 15, quad = lane >> 4;
    f32x4_t acc[4][4] = {};

    for (int k0 = 0; k0 < C_; k0 += 64) {
#pragma unroll
        for (int i = 0; i < 4; ++i) {
            int l = i * 256 + tid;         // 0..1023: 128 rows x 8 chunks
            int r = l >> 3, c8 = (l & 7) << 3;
            *(uint4*)&As[r][c8] = *(const uint4*)&A[(size_t)(bm + r) * C_ + k0 + c8];
            *(uint4*)&Bs[r][c8] = *(const uint4*)&W[(size_t)(bn + r) * C_ + k0 + c8];
        }
        __syncthreads();
#pragma unroll
        for (int ks = 0; ks < 2; ++ks) {
            bf16x8_t af[4], bf[4];
#pragma unroll
            for (int t = 0; t < 4; ++t)
                af[t] = *(const bf16x8_t*)&As[wm * 64 + t * 16 + l16][ks * 32 + quad * 8];
#pragma unroll
            for (int t = 0; t < 4; ++t)
                bf[t] = *(const bf16x8_t*)&Bs[wn * 64 + t * 16 + l16][ks * 32 + quad * 8];
#pragma unroll
            for (int i = 0; i < 4; ++i)
#pragma unroll
                for (int j = 0; j < 4; ++j)
                    acc[i][j] = __builtin_amdgcn_mfma_f32_16x16x32_bf16(af[i], bf[j], acc[i][j], 0, 0, 0);
        }
        __syncthreads();
    }
#pragma unroll
    for (int tn = 0; tn < 4; ++tn) {
        const int col = bn + wn * 64 + tn * 16 + l16;
        const float bv = bias[col];
#pragma unroll
        for (int tm = 0; tm < 4; ++tm) {
            const int row0 = bm + wm * 64 + tm * 16 + quad * 4;
#pragma unroll
            for (int r = 0; r < 4; ++r) {
                float val = acc[tm][tn][r] + bv;
                if (outb) outb[(size_t)(row0 + r) * ostride + ooff + col] = f2bf(val);
                else      outf[(size_t)(row0 + r) * C_ + col] = val;
            }
        }
    }
}

__global__ __launch_bounds__(256) void gemm_qkv(
        const unsigned short* __restrict__ xb, const unsigned short* __restrict__ Wb,
        const float* __restrict__ bq, const float* __restrict__ bk, const float* __restrict__ bv,
        unsigned short* __restrict__ qb, unsigned short* __restrict__ kvb) {
    int z = blockIdx.z;
    const unsigned short* W = Wb + (size_t)z * (C_ * C_);
    const float* bias = (z == 0) ? bq : (z == 1) ? bk : bv;
    unsigned short* outb = (z == 0) ? qb : kvb;
    int stride = (z == 0) ? 256 : 512;
    int off = (z == 2) ? 256 : 0;
    gemm_mfma_body(xb, W, bias, outb, nullptr, stride, off, blockIdx.x * 128, blockIdx.y * 128);
}

__global__ __launch_bounds__(256) void gemm_proj(
        const unsigned short* __restrict__ attnb, const unsigned short* __restrict__ Wxb,
        const float* __restrict__ bx, float* __restrict__ out) {
    gemm_mfma_body(attnb, Wxb, bx, nullptr, out, 0, 0, blockIdx.x * 128, blockIdx.y * 128);
}

// ---------------- edge attention ----------------
// One wave per sequence row s, both batch slices: lanes 0-31 -> b=0, 32-63 -> b=1.
// Each lane holds 8 channels (bf16); head = (lane&31)>>2; dot reduce over quad.

__global__ __launch_bounds__(256) void attn_edge(
        const unsigned short* __restrict__ qb, const unsigned short* __restrict__ kvb,
        const int* __restrict__ base, const int* __restrict__ kid,
        unsigned short* __restrict__ attnb) {
    const int lane = threadIdx.x & 63;
    const int wave = threadIdx.x >> 6;
    const int s = blockIdx.x * 4 + wave;
    const int half = lane >> 5, hl = lane & 31;
    const int e0 = __builtin_amdgcn_readfirstlane(base[s]);
    const int e1 = __builtin_amdgcn_readfirstlane(base[s + 1]);

    const uint4 qq = *((const uint4*)(qb + (size_t)(s * 2 + half) * C_) + hl);
    const float q0 = bflo(qq.x), q1 = bfhi(qq.x), q2 = bflo(qq.y), q3 = bfhi(qq.y);
    const float q4 = bflo(qq.z), q5 = bfhi(qq.z), q6 = bflo(qq.w), q7 = bfhi(qq.w);

    float a0 = 0.f, a1 = 0.f, a2 = 0.f, a3 = 0.f, a4 = 0.f, a5 = 0.f, a6 = 0.f, a7 = 0.f;
    float wsum = 0.f;
    const float scale = 0.17677669529663687f;   // 1/sqrt(32)

    for (int j = e0; j < e1; ++j) {
        const int ke = kid[j];
        const uint4* kvp = (const uint4*)(kvb + (size_t)(ke * 2 + half) * 512);
        const uint4 kk = kvp[hl];
        const uint4 vv = kvp[32 + hl];
        float p = q0 * bflo(kk.x) + q1 * bfhi(kk.x)
                + q2 * bflo(kk.y) + q3 * bfhi(kk.y)
                + q4 * bflo(kk.z) + q5 * bfhi(kk.z)
                + q6 * bflo(kk.w) + q7 * bfhi(kk.w);
        p += __shfl_xor(p, 1);
        p += __shfl_xor(p, 2);
        const float w = __expf(p * scale);
        a0 = fmaf(w, bflo(vv.x), a0); a1 = fmaf(w, bfhi(vv.x), a1);
        a2 = fmaf(w, bflo(vv.y), a2); a3 = fmaf(w, bfhi(vv.y), a3);
        a4 = fmaf(w, bflo(vv.z), a4); a5 = fmaf(w, bfhi(vv.z), a5);
        a6 = fmaf(w, bflo(vv.w), a6); a7 = fmaf(w, bfhi(vv.w), a7);
        wsum += w;
    }
    const float inv = 1.0f / wsum;
    uint4 o;
    o.x = (unsigned)f2bf(a0 * inv) | ((unsigned)f2bf(a1 * inv) << 16);
    o.y = (unsigned)f2bf(a2 * inv) | ((unsigned)f2bf(a3 * inv) << 16);
    o.z = (unsigned)f2bf(a4 * inv) | ((unsigned)f2bf(a5 * inv) << 16);
    o.w = (unsigned)f2bf(a6 * inv) | ((unsigned)f2bf(a7 * inv) << 16);
    *((uint4*)(attnb + (size_t)(s * 2 + half) * C_) + hl) = o;
}

// ---------------- launch ----------------

extern "C" void kernel_launch(void* const* d_in, const int* in_sizes, int n_in,
                              void* d_out, int out_size, void* d_ws, size_t ws_size,
                              hipStream_t stream) {
    const float* x  = (const float*)d_in[0];
    const int* q_id = (const int*)d_in[1];
    const int* k_id = (const int*)d_in[2];
    const float* Wq = (const float*)d_in[3];
    const float* bq = (const float*)d_in[4];
    const float* Wk = (const float*)d_in[5];
    const float* bk = (const float*)d_in[6];
    const float* Wv = (const float*)d_in[7];
    const float* bv = (const float*)d_in[8];
    const float* Wx = (const float*)d_in[9];
    const float* bx = (const float*)d_in[10];
    float* out = (float*)d_out;

    char* ws = (char*)d_ws;
    unsigned short* xb    = (unsigned short*)ws;                 ws += (size_t)MR * C_ * 2;   // 4 MB
    unsigned short* qb    = (unsigned short*)ws;                 ws += (size_t)MR * C_ * 2;   // 4 MB
    unsigned short* kvb   = (unsigned short*)ws;                 ws += (size_t)MR * 512 * 2;  // 8 MB
    unsigned short* attnb = (unsigned short*)ws;                 ws += (size_t)MR * C_ * 2;   // 4 MB
    unsigned short* Wb    = (unsigned short*)ws;                 ws += (size_t)4 * C_ * C_ * 2; // 512 KB
    int* count      = (int*)ws;                                  ws += S_ * 4;
    int* base       = (int*)ws;                                  ws += (S_ + 1) * 4;
    int* cursor     = (int*)ws;                                  ws += S_ * 4;
    int* kid_sorted = (int*)ws;

    hipMemsetAsync(count, 0, S_ * sizeof(int), stream);
    hist_kernel<<<E_ / 256, 256, 0, stream>>>(q_id, count);
    scan_kernel<<<1, 1024, 0, stream>>>(count, base, cursor);
    scatter_kernel<<<E_ / 256, 256, 0, stream>>>(q_id, k_id, cursor, kid_sorted);

    cast_x_kernel<<<(MR * C_ / 8) / 256, 256, 0, stream>>>(x, xb);
    cast_w4_kernel<<<dim3((C_ * C_ / 8) / 256, 1, 4), 256, 0, stream>>>(Wq, Wk, Wv, Wx, Wb);

    gemm_qkv<<<dim3(MR / 128, C_ / 128, 3), 256, 0, stream>>>(xb, Wb, bq, bk, bv, qb, kvb);

    attn_edge<<<S_ / 4, 256, 0, stream>>>(qb, kvb, base, kid_sorted, attnb);

    gemm_proj<<<dim3(MR / 128, C_ / 128), 256, 0, stream>>>(attnb, Wb + (size_t)3 * C_ * C_, bx, out);
}

// Round 3
// 157.242 us; speedup vs baseline: 1.4791x; 1.0374x over previous
//
#include <hip/hip_runtime.h>

// Problem constants (fixed by the dataset)
constexpr int S_  = 4096;
constexpr int B_  = 2;
constexpr int C_  = 256;
constexpr int H_  = 8;
constexpr int E_  = 131072;
constexpr int CC_ = 32;
constexpr int MR  = S_ * B_;   // 8192 rows for all GEMMs

typedef __attribute__((ext_vector_type(8))) short bf16x8_t;
typedef __attribute__((ext_vector_type(4))) float f32x4_t;

__device__ __forceinline__ unsigned short f2bf(float f) {
    unsigned int u = __float_as_uint(f);
    u += 0x7fffu + ((u >> 16) & 1u);   // round-to-nearest-even
    return (unsigned short)(u >> 16);
}
__device__ __forceinline__ float bflo(unsigned int u) { return __uint_as_float(u << 16); }
__device__ __forceinline__ float bfhi(unsigned int u) { return __uint_as_float(u & 0xffff0000u); }

__device__ __forceinline__ void cast8(const float* __restrict__ src, unsigned short* __restrict__ dst, int i) {
    const float4* s = (const float4*)src + (size_t)i * 2;
    float4 a = s[0], b = s[1];
    uint4 o;
    o.x = (unsigned)f2bf(a.x) | ((unsigned)f2bf(a.y) << 16);
    o.y = (unsigned)f2bf(a.z) | ((unsigned)f2bf(a.w) << 16);
    o.z = (unsigned)f2bf(b.x) | ((unsigned)f2bf(b.y) << 16);
    o.w = (unsigned)f2bf(b.z) | ((unsigned)f2bf(b.w) << 16);
    *((uint4*)dst + i) = o;
}

// ---------------- K1: histogram + casts (independent work, one launch) ----------------
// blocks [0,512): hist; [512,1536): cast x; [1536,1664): cast W (4 matrices)

__global__ __launch_bounds__(256) void prep_kernel(
        const int* __restrict__ q_id, int* __restrict__ count,
        const float* __restrict__ x, unsigned short* __restrict__ xb,
        const float* __restrict__ Wq, const float* __restrict__ Wk,
        const float* __restrict__ Wv, const float* __restrict__ Wx,
        unsigned short* __restrict__ Wb) {
    const int bid = blockIdx.x, tid = threadIdx.x;
    if (bid < 512) {
        atomicAdd(&count[q_id[bid * 256 + tid]], 1);
    } else if (bid < 1536) {
        cast8(x, xb, (bid - 512) * 256 + tid);
    } else {
        int idx = bid - 1536;
        int z = idx >> 5;
        const float* src = (z == 0) ? Wq : (z == 1) ? Wk : (z == 2) ? Wv : Wx;
        cast8(src, Wb + (size_t)z * (C_ * C_), (idx & 31) * 256 + tid);
    }
}

// ---------------- K2: scan (shfl-based, 2 barriers) ----------------

__global__ __launch_bounds__(1024) void scan_kernel(const int* __restrict__ count,
                                                    int* __restrict__ base,
                                                    int* __restrict__ cursor) {
    __shared__ int wsums[16];
    const int t = threadIdx.x, lane = t & 63, w = t >> 6;
    int c0 = count[4 * t + 0], c1 = count[4 * t + 1];
    int c2 = count[4 * t + 2], c3 = count[4 * t + 3];
    int tsum = c0 + c1 + c2 + c3;
    // wave inclusive scan
    int x = tsum;
#pragma unroll
    for (int off = 1; off < 64; off <<= 1) {
        int y = __shfl_up(x, off);
        if (lane >= off) x += y;
    }
    if (lane == 63) wsums[w] = x;
    __syncthreads();
    if (t == 0) {
        int run = 0;
#pragma unroll
        for (int i = 0; i < 16; ++i) { int v = wsums[i]; wsums[i] = run; run += v; }
        base[S_] = run;
    }
    __syncthreads();
    int excl = x - tsum + wsums[w];
    int b0 = excl, b1 = b0 + c0, b2 = b1 + c1, b3 = b2 + c2;
    base[4 * t + 0] = b0; base[4 * t + 1] = b1;
    base[4 * t + 2] = b2; base[4 * t + 3] = b3;
    cursor[4 * t + 0] = b0; cursor[4 * t + 1] = b1;
    cursor[4 * t + 2] = b2; cursor[4 * t + 3] = b3;
}

// ---------------- bf16 MFMA GEMM body: Out[M,N] = A[M,K] @ W[N,K]^T + bias ----------------
// BM=128, NB in {128,64}; 256 threads (4 waves 2x2); 16x16x32 mfma; LDS-staged epilogue.

template <int NB, bool BF16OUT>
__device__ __forceinline__ void gemm_body(
        const unsigned short* __restrict__ A, const unsigned short* __restrict__ W,
        const float* __restrict__ bias,
        unsigned short* __restrict__ outb, float* __restrict__ outf,
        int ostride, int ooff, int bm, int bn) {
    constexpr int NT = NB / 32;                    // n-tiles per wave
    __shared__ __align__(16) unsigned short As[128][72];
    __shared__ __align__(16) unsigned short Bs[NB][72];
    const int tid = threadIdx.x;
    const int lane = tid & 63, wave = tid >> 6;
    const int wm = wave >> 1, wn = wave & 1;
    const int l16 = lane & 15, quad = lane >> 4;
    f32x4_t acc[4][NT] = {};

    for (int k0 = 0; k0 < C_; k0 += 64) {
#pragma unroll
        for (int i = 0; i < 4; ++i) {
            int l = i * 256 + tid;
            int r = l >> 3, c8 = (l & 7) << 3;
            *(uint4*)&As[r][c8] = *(const uint4*)&A[(size_t)(bm + r) * C_ + k0 + c8];
        }
#pragma unroll
        for (int i = 0; i < NT; ++i) {
            int l = i * 256 + tid;
            int r = l >> 3, c8 = (l & 7) << 3;
            *(uint4*)&Bs[r][c8] = *(const uint4*)&W[(size_t)(bn + r) * C_ + k0 + c8];
        }
        __syncthreads();
#pragma unroll
        for (int ks = 0; ks < 2; ++ks) {
            bf16x8_t af[4], bf[NT];
#pragma unroll
            for (int t = 0; t < 4; ++t)
                af[t] = *(const bf16x8_t*)&As[wm * 64 + t * 16 + l16][ks * 32 + quad * 8];
#pragma unroll
            for (int t = 0; t < NT; ++t)
                bf[t] = *(const bf16x8_t*)&Bs[wn * (NB / 2) + t * 16 + l16][ks * 32 + quad * 8];
#pragma unroll
            for (int i = 0; i < 4; ++i)
#pragma unroll
                for (int j = 0; j < NT; ++j)
                    acc[i][j] = __builtin_amdgcn_mfma_f32_16x16x32_bf16(af[i], bf[j], acc[i][j], 0, 0, 0);
        }
        __syncthreads();
    }

    // bias per owned column
    float bcol[NT];
#pragma unroll
    for (int tn = 0; tn < NT; ++tn)
        bcol[tn] = bias[bn + wn * (NB / 2) + tn * 16 + l16];

    // epilogue: stage 32-row x NB chunks in LDS (row stride 272B), store vectorized
    char* buf = (char*)&As[0][0];
#pragma unroll
    for (int tm = 0; tm < 4; ++tm) {
        __syncthreads();
        const int lrow = wm * 16 + quad * 4;
#pragma unroll
        for (int tn = 0; tn < NT; ++tn) {
            const int col = wn * (NB / 2) + tn * 16 + l16;
#pragma unroll
            for (int r = 0; r < 4; ++r) {
                float val = acc[tm][tn][r] + bcol[tn];
                if (BF16OUT) ((unsigned short*)(buf + (size_t)(lrow + r) * 272))[col] = f2bf(val);
                else         ((float*)(buf + (size_t)(lrow + r) * 272))[col] = val;
            }
        }
        __syncthreads();
        // 32 rows x NB cols = 512 16B vectors, 2 per thread
#pragma unroll
        for (int i = 0; i < 2; ++i) {
            int f = tid * 2 + i;
            int lr = f >> 4, cc = f & 15;
            int grow = bm + (lr >> 4) * 64 + tm * 16 + (lr & 15);
            if (BF16OUT)
                *(uint4*)&outb[(size_t)grow * ostride + ooff + bn + cc * 8] =
                    *(const uint4*)(buf + (size_t)lr * 272 + cc * 16);
            else
                *(float4*)&outf[(size_t)grow * C_ + bn + cc * 4] =
                    *(const float4*)(buf + (size_t)lr * 272 + cc * 16);
        }
    }
}

// ---------------- K3: scatter + QKV GEMM (independent, one launch) ----------------
// blocks [0,512): scatter; [512,896): qkv gemm (z=gb>>7, 64 m-blocks x 2 n-blocks)

__global__ __launch_bounds__(256) void scatter_qkv_kernel(
        const int* __restrict__ q_id, const int* __restrict__ k_id,
        int* __restrict__ cursor, int* __restrict__ koff_sorted,
        const unsigned short* __restrict__ xb, const unsigned short* __restrict__ Wb,
        const float* __restrict__ bq, const float* __restrict__ bk, const float* __restrict__ bv,
        unsigned short* __restrict__ qb, unsigned short* __restrict__ kvb) {
    const int bid = blockIdx.x;
    if (bid < 512) {
        int e = bid * 256 + threadIdx.x;
        int pos = atomicAdd(&cursor[q_id[e]], 1);
        koff_sorted[pos] = k_id[e] << 10;          // element offset into kvb
        return;
    }
    int gb = bid - 512;
    int z = gb >> 7, rem = gb & 127;
    int bm = (rem >> 1) * 128, bn = (rem & 1) * 128;
    const unsigned short* W = Wb + (size_t)z * (C_ * C_);
    const float* bias = (z == 0) ? bq : (z == 1) ? bk : bv;
    unsigned short* outb = (z == 0) ? qb : kvb;
    int stride = (z == 0) ? 256 : 512;
    int off = (z == 2) ? 256 : 0;
    gemm_body<128, true>(xb, W, bias, outb, nullptr, stride, off, bm, bn);
}

// ---------------- K4: edge attention ----------------
// Block = 4 waves = 2 seq rows x 2 edge-parts. Wave covers both batch slices
// (lanes 0-31 -> b=0, 32-63 -> b=1), 8 bf16 channels/lane; head dot = quad shfl.

__global__ __launch_bounds__(256) void attn_edge(
        const unsigned short* __restrict__ qb, const unsigned short* __restrict__ kvb,
        const int* __restrict__ base, const int* __restrict__ koff,
        unsigned short* __restrict__ attnb) {
    __shared__ float red[2][64][9];
    const int lane = threadIdx.x & 63;
    const int wave = threadIdx.x >> 6;
    const int rw = wave >> 1, part = wave & 1;
    const int s = blockIdx.x * 2 + rw;
    const int half = lane >> 5, hl = lane & 31;
    const int e0 = __builtin_amdgcn_readfirstlane(base[s]);
    const int e1 = __builtin_amdgcn_readfirstlane(base[s + 1]);

    const uint4 qq = *((const uint4*)(qb + (size_t)(s * 2 + half) * C_) + hl);
    const float q0 = bflo(qq.x), q1 = bfhi(qq.x), q2 = bflo(qq.y), q3 = bfhi(qq.y);
    const float q4 = bflo(qq.z), q5 = bfhi(qq.z), q6 = bflo(qq.w), q7 = bfhi(qq.w);

    float a0 = 0.f, a1 = 0.f, a2 = 0.f, a3 = 0.f, a4 = 0.f, a5 = 0.f, a6 = 0.f, a7 = 0.f;
    float wsum = 0.f;
    const float scale = 0.17677669529663687f;   // 1/sqrt(32)

    for (int j = e0 + part; j < e1; j += 2) {
        const int kb = koff[j];
        const uint4* kvp = (const uint4*)(kvb + kb + half * 512);
        const uint4 kk = kvp[hl];
        const uint4 vv = kvp[32 + hl];
        float p = q0 * bflo(kk.x) + q1 * bfhi(kk.x)
                + q2 * bflo(kk.y) + q3 * bfhi(kk.y)
                + q4 * bflo(kk.z) + q5 * bfhi(kk.z)
                + q6 * bflo(kk.w) + q7 * bfhi(kk.w);
        p += __shfl_xor(p, 1);
        p += __shfl_xor(p, 2);
        const float w = __expf(p * scale);
        a0 = fmaf(w, bflo(vv.x), a0); a1 = fmaf(w, bfhi(vv.x), a1);
        a2 = fmaf(w, bflo(vv.y), a2); a3 = fmaf(w, bfhi(vv.y), a3);
        a4 = fmaf(w, bflo(vv.z), a4); a5 = fmaf(w, bfhi(vv.z), a5);
        a6 = fmaf(w, bflo(vv.w), a6); a7 = fmaf(w, bfhi(vv.w), a7);
        wsum += w;
    }

    if (part == 1) {
        float* r = red[rw][lane];
        r[0] = a0; r[1] = a1; r[2] = a2; r[3] = a3;
        r[4] = a4; r[5] = a5; r[6] = a6; r[7] = a7; r[8] = wsum;
    }
    __syncthreads();
    if (part == 0) {
        const float* r = red[rw][lane];
        a0 += r[0]; a1 += r[1]; a2 += r[2]; a3 += r[3];
        a4 += r[4]; a5 += r[5]; a6 += r[6]; a7 += r[7]; wsum += r[8];
        const float inv = 1.0f / wsum;
        uint4 o;
        o.x = (unsigned)f2bf(a0 * inv) | ((unsigned)f2bf(a1 * inv) << 16);
        o.y = (unsigned)f2bf(a2 * inv) | ((unsigned)f2bf(a3 * inv) << 16);
        o.z = (unsigned)f2bf(a4 * inv) | ((unsigned)f2bf(a5 * inv) << 16);
        o.w = (unsigned)f2bf(a6 * inv) | ((unsigned)f2bf(a7 * inv) << 16);
        *((uint4*)(attnb + (size_t)(s * 2 + half) * C_) + hl) = o;
    }
}

// ---------------- K5: output projection (128x64 tiles -> 256 blocks) ----------------

__global__ __launch_bounds__(256) void gemm_proj(
        const unsigned short* __restrict__ attnb, const unsigned short* __restrict__ Wxb,
        const float* __restrict__ bx, float* __restrict__ out) {
    gemm_body<64, false>(attnb, Wxb, bx, nullptr, out, 0, 0, blockIdx.x * 128, blockIdx.y * 64);
}

// ---------------- launch ----------------

extern "C" void kernel_launch(void* const* d_in, const int* in_sizes, int n_in,
                              void* d_out, int out_size, void* d_ws, size_t ws_size,
                              hipStream_t stream) {
    const float* x  = (const float*)d_in[0];
    const int* q_id = (const int*)d_in[1];
    const int* k_id = (const int*)d_in[2];
    const float* Wq = (const float*)d_in[3];
    const float* bq = (const float*)d_in[4];
    const float* Wk = (const float*)d_in[5];
    const float* bk = (const float*)d_in[6];
    const float* Wv = (const float*)d_in[7];
    const float* bv = (const float*)d_in[8];
    const float* Wx = (const float*)d_in[9];
    const float* bx = (const float*)d_in[10];
    float* out = (float*)d_out;

    char* ws = (char*)d_ws;
    unsigned short* xb    = (unsigned short*)ws;                 ws += (size_t)MR * C_ * 2;
    unsigned short* qb    = (unsigned short*)ws;                 ws += (size_t)MR * C_ * 2;
    unsigned short* kvb   = (unsigned short*)ws;                 ws += (size_t)MR * 512 * 2;
    unsigned short* attnb = (unsigned short*)ws;                 ws += (size_t)MR * C_ * 2;
    unsigned short* Wb    = (unsigned short*)ws;                 ws += (size_t)4 * C_ * C_ * 2;
    int* count       = (int*)ws;                                 ws += S_ * 4;
    int* base        = (int*)ws;                                 ws += (S_ + 1) * 4;
    int* cursor      = (int*)ws;                                 ws += S_ * 4;
    int* koff_sorted = (int*)ws;

    hipMemsetAsync(count, 0, S_ * sizeof(int), stream);
    prep_kernel<<<1664, 256, 0, stream>>>(q_id, count, x, xb, Wq, Wk, Wv, Wx, Wb);
    scan_kernel<<<1, 1024, 0, stream>>>(count, base, cursor);
    scatter_qkv_kernel<<<896, 256, 0, stream>>>(q_id, k_id, cursor, koff_sorted,
                                                xb, Wb, bq, bk, bv, qb, kvb);
    attn_edge<<<S_ / 2, 256, 0, stream>>>(qb, kvb, base, koff_sorted, attnb);
    gemm_proj<<<dim3(MR / 128, C_ / 64), 256, 0, stream>>>(
        attnb, Wb + (size_t)3 * C_ * C_, bx, out);
}

// Round 5
// 155.453 us; speedup vs baseline: 1.4961x; 1.0115x over previous
//
#include <hip/hip_runtime.h>

// Problem constants (fixed by the dataset)
constexpr int S_  = 4096;
constexpr int B_  = 2;
constexpr int C_  = 256;
constexpr int H_  = 8;
constexpr int E_  = 131072;
constexpr int CC_ = 32;
constexpr int MR  = S_ * B_;   // 8192 rows for all GEMMs

typedef __attribute__((ext_vector_type(8))) short bf16x8_t;
typedef __attribute__((ext_vector_type(4))) float f32x4_t;

__device__ __forceinline__ unsigned short f2bf(float f) {
    unsigned int u = __float_as_uint(f);
    u += 0x7fffu + ((u >> 16) & 1u);   // round-to-nearest-even
    return (unsigned short)(u >> 16);
}
__device__ __forceinline__ float bflo(unsigned int u) { return __uint_as_float(u << 16); }
__device__ __forceinline__ float bfhi(unsigned int u) { return __uint_as_float(u & 0xffff0000u); }

__device__ __forceinline__ void cast8(const float* __restrict__ src, unsigned short* __restrict__ dst, int i) {
    const float4* s = (const float4*)src + (size_t)i * 2;
    float4 a = s[0], b = s[1];
    uint4 o;
    o.x = (unsigned)f2bf(a.x) | ((unsigned)f2bf(a.y) << 16);
    o.y = (unsigned)f2bf(a.z) | ((unsigned)f2bf(a.w) << 16);
    o.z = (unsigned)f2bf(b.x) | ((unsigned)f2bf(b.y) << 16);
    o.w = (unsigned)f2bf(b.z) | ((unsigned)f2bf(b.w) << 16);
    *((uint4*)dst + i) = o;
}

// ---------------- K1: histogram + casts (independent work, one launch) ----------------
// blocks [0,512): hist; [512,1536): cast x; [1536,1664): cast W (4 matrices)

__global__ __launch_bounds__(256) void prep_kernel(
        const int* __restrict__ q_id, int* __restrict__ count,
        const float* __restrict__ x, unsigned short* __restrict__ xb,
        const float* __restrict__ Wq, const float* __restrict__ Wk,
        const float* __restrict__ Wv, const float* __restrict__ Wx,
        unsigned short* __restrict__ Wb) {
    const int bid = blockIdx.x, tid = threadIdx.x;
    if (bid < 512) {
        atomicAdd(&count[q_id[bid * 256 + tid]], 1);
    } else if (bid < 1536) {
        cast8(x, xb, (bid - 512) * 256 + tid);
    } else {
        int idx = bid - 1536;
        int z = idx >> 5;
        const float* src = (z == 0) ? Wq : (z == 1) ? Wk : (z == 2) ? Wv : Wx;
        cast8(src, Wb + (size_t)z * (C_ * C_), (idx & 31) * 256 + tid);
    }
}

// ---------------- K2: scan (shfl-based, 2 barriers) ----------------

__global__ __launch_bounds__(1024) void scan_kernel(const int* __restrict__ count,
                                                    int* __restrict__ base,
                                                    int* __restrict__ cursor) {
    __shared__ int wsums[16];
    const int t = threadIdx.x, lane = t & 63, w = t >> 6;
    int c0 = count[4 * t + 0], c1 = count[4 * t + 1];
    int c2 = count[4 * t + 2], c3 = count[4 * t + 3];
    int tsum = c0 + c1 + c2 + c3;
    int x = tsum;
#pragma unroll
    for (int off = 1; off < 64; off <<= 1) {
        int y = __shfl_up(x, off);
        if (lane >= off) x += y;
    }
    if (lane == 63) wsums[w] = x;
    __syncthreads();
    if (t == 0) {
        int run = 0;
#pragma unroll
        for (int i = 0; i < 16; ++i) { int v = wsums[i]; wsums[i] = run; run += v; }
        base[S_] = run;
    }
    __syncthreads();
    int excl = x - tsum + wsums[w];
    int b0 = excl, b1 = b0 + c0, b2 = b1 + c1, b3 = b2 + c2;
    base[4 * t + 0] = b0; base[4 * t + 1] = b1;
    base[4 * t + 2] = b2; base[4 * t + 3] = b3;
    cursor[4 * t + 0] = b0; cursor[4 * t + 1] = b1;
    cursor[4 * t + 2] = b2; cursor[4 * t + 3] = b3;
}

// ---------------- bf16 MFMA GEMM body: Out[M,N] = A[M,K] @ W[N,K]^T + bias ----------------
// BM=128, NB in {128,64}; 256 threads (4 waves 2x2); 16x16x32 mfma; LDS-staged epilogue.

template <int NB, bool BF16OUT>
__device__ __forceinline__ void gemm_body(
        const unsigned short* __restrict__ A, const unsigned short* __restrict__ W,
        const float* __restrict__ bias,
        unsigned short* __restrict__ outb, float* __restrict__ outf,
        int ostride, int ooff, int bm, int bn) {
    constexpr int NT = NB / 32;                    // n-tiles per wave
    __shared__ __align__(16) unsigned short As[128][72];
    __shared__ __align__(16) unsigned short Bs[NB][72];
    const int tid = threadIdx.x;
    const int lane = tid & 63, wave = tid >> 6;
    const int wm = wave >> 1, wn = wave & 1;
    const int l16 = lane & 15, quad = lane >> 4;
    f32x4_t acc[4][NT] = {};

    for (int k0 = 0; k0 < C_; k0 += 64) {
#pragma unroll
        for (int i = 0; i < 4; ++i) {
            int l = i * 256 + tid;
            int r = l >> 3, c8 = (l & 7) << 3;
            *(uint4*)&As[r][c8] = *(const uint4*)&A[(size_t)(bm + r) * C_ + k0 + c8];
        }
#pragma unroll
        for (int i = 0; i < NB / 32; ++i) {
            int l = i * 256 + tid;
            int r = l >> 3, c8 = (l & 7) << 3;
            *(uint4*)&Bs[r][c8] = *(const uint4*)&W[(size_t)(bn + r) * C_ + k0 + c8];
        }
        __syncthreads();
#pragma unroll
        for (int ks = 0; ks < 2; ++ks) {
            bf16x8_t af[4], bf[NT];
#pragma unroll
            for (int t = 0; t < 4; ++t)
                af[t] = *(const bf16x8_t*)&As[wm * 64 + t * 16 + l16][ks * 32 + quad * 8];
#pragma unroll
            for (int t = 0; t < NT; ++t)
                bf[t] = *(const bf16x8_t*)&Bs[wn * (NB / 2) + t * 16 + l16][ks * 32 + quad * 8];
#pragma unroll
            for (int i = 0; i < 4; ++i)
#pragma unroll
                for (int j = 0; j < NT; ++j)
                    acc[i][j] = __builtin_amdgcn_mfma_f32_16x16x32_bf16(af[i], bf[j], acc[i][j], 0, 0, 0);
        }
        __syncthreads();
    }

    float bcol[NT];
#pragma unroll
    for (int tn = 0; tn < NT; ++tn)
        bcol[tn] = bias[bn + wn * (NB / 2) + tn * 16 + l16];

    // epilogue: stage 32-row chunks in LDS, store vectorized
    char* buf = (char*)&As[0][0];
#pragma unroll
    for (int tm = 0; tm < 4; ++tm) {
        __syncthreads();
        const int lrow = wm * 16 + quad * 4;
#pragma unroll
        for (int tn = 0; tn < NT; ++tn) {
            const int col = wn * (NB / 2) + tn * 16 + l16;
#pragma unroll
            for (int r = 0; r < 4; ++r) {
                float val = acc[tm][tn][r] + bcol[tn];
                if (BF16OUT) ((unsigned short*)(buf + (size_t)(lrow + r) * 272))[col] = f2bf(val);
                else         ((float*)(buf + (size_t)(lrow + r) * 272))[col] = val;
            }
        }
        __syncthreads();
#pragma unroll
        for (int i = 0; i < 2; ++i) {
            int f = tid * 2 + i;
            int lr = f >> 4, cc = f & 15;
            int grow = bm + (lr >> 4) * 64 + tm * 16 + (lr & 15);
            if (BF16OUT) {
                if (NB == 128 || i == 0) {
                    int f2 = (NB == 128) ? f : tid;
                    lr = f2 >> 3; cc = f2 & 7;
                    grow = bm + (lr >> 4) * 64 + tm * 16 + (lr & 15);
                    if (NB == 128) { lr = f2 >> 4; cc = f2 & 15; grow = bm + (lr >> 4) * 64 + tm * 16 + (lr & 15);
                        *(uint4*)&outb[(size_t)grow * ostride + ooff + bn + cc * 8] =
                            *(const uint4*)(buf + (size_t)lr * 272 + cc * 16);
                    } else {
                        *(uint4*)&outb[(size_t)grow * ostride + ooff + bn + cc * 8] =
                            *(const uint4*)(buf + (size_t)lr * 272 + cc * 16);
                    }
                }
            } else {
                *(float4*)&outf[(size_t)grow * C_ + bn + cc * 4] =
                    *(const float4*)(buf + (size_t)lr * 272 + cc * 16);
            }
        }
    }
}

// ---------------- K3: scatter + QKV GEMM (independent, one launch) ----------------

__global__ __launch_bounds__(256) void scatter_qkv_kernel(
        const int* __restrict__ q_id, const int* __restrict__ k_id,
        int* __restrict__ cursor, int* __restrict__ koff_sorted,
        const unsigned short* __restrict__ xb, const unsigned short* __restrict__ Wb,
        const float* __restrict__ bq, const float* __restrict__ bk, const float* __restrict__ bv,
        unsigned short* __restrict__ qb, unsigned short* __restrict__ kvb) {
    const int bid = blockIdx.x;
    if (bid < 512) {
        int e = bid * 256 + threadIdx.x;
        int pos = atomicAdd(&cursor[q_id[e]], 1);
        koff_sorted[pos] = k_id[e] << 10;          // element offset into kvb
        return;
    }
    int gb = bid - 512;
    int z = gb >> 7, rem = gb & 127;
    int bm = (rem >> 1) * 128, bn = (rem & 1) * 128;
    const unsigned short* W = Wb + (size_t)z * (C_ * C_);
    const float* bias = (z == 0) ? bq : (z == 1) ? bk : bv;
    unsigned short* outb = (z == 0) ? qb : kvb;
    int stride = (z == 0) ? 256 : 512;
    int off = (z == 2) ? 256 : 0;
    gemm_body<128, true>(xb, W, bias, outb, nullptr, stride, off, bm, bn);
}

// ---------------- K4: edge attention (pipelined gather) ----------------
// Block = 4 waves = 2 seq rows x 2 edge-parts. Wave covers both batch slices
// (lanes 0-31 -> b=0, 32-63 -> b=1), 8 bf16 channels/lane; head dot = quad shfl.
// Per 64-edge chunk: coalesced per-lane koff preload + readlane broadcast;
// 2-slot software pipeline keeps 2 gathers in flight per wave.

__global__ __launch_bounds__(256) void attn_edge(
        const unsigned short* __restrict__ qb, const unsigned short* __restrict__ kvb,
        const int* __restrict__ base, const int* __restrict__ koff,
        unsigned short* __restrict__ attnb) {
    __shared__ float red[2][64][9];
    const int lane = threadIdx.x & 63;
    const int wave = threadIdx.x >> 6;
    const int rw = wave >> 1, part = wave & 1;
    const int s = blockIdx.x * 2 + rw;
    const int half = lane >> 5, hl = lane & 31;
    const int e0 = __builtin_amdgcn_readfirstlane(base[s]);
    const int e1 = __builtin_amdgcn_readfirstlane(base[s + 1]);

    const uint4 qq = *((const uint4*)(qb + (size_t)(s * 2 + half) * C_) + hl);
    const float q0 = bflo(qq.x), q1 = bfhi(qq.x), q2 = bflo(qq.y), q3 = bfhi(qq.y);
    const float q4 = bflo(qq.z), q5 = bfhi(qq.z), q6 = bflo(qq.w), q7 = bfhi(qq.w);

    float a0 = 0.f, a1 = 0.f, a2 = 0.f, a3 = 0.f, a4 = 0.f, a5 = 0.f, a6 = 0.f, a7 = 0.f;
    float wsum = 0.f;
    const float scale = 0.17677669529663687f;   // 1/sqrt(32)

    auto edge = [&](const uint4& kk, const uint4& vv) {
        float p = q0 * bflo(kk.x) + q1 * bfhi(kk.x)
                + q2 * bflo(kk.y) + q3 * bfhi(kk.y)
                + q4 * bflo(kk.z) + q5 * bfhi(kk.z)
                + q6 * bflo(kk.w) + q7 * bfhi(kk.w);
        p += __shfl_xor(p, 1);
        p += __shfl_xor(p, 2);
        const float w = __expf(p * scale);
        a0 = fmaf(w, bflo(vv.x), a0); a1 = fmaf(w, bfhi(vv.x), a1);
        a2 = fmaf(w, bflo(vv.y), a2); a3 = fmaf(w, bfhi(vv.y), a3);
        a4 = fmaf(w, bflo(vv.z), a4); a5 = fmaf(w, bfhi(vv.z), a5);
        a6 = fmaf(w, bflo(vv.w), a6); a7 = fmaf(w, bfhi(vv.w), a7);
        wsum += w;
    };
    auto fetch = [&](int my, int t, uint4& kk, uint4& vv) {
        int o = __builtin_amdgcn_readlane(my, part + 2 * t);   // wave-uniform index
        const uint4* p = (const uint4*)(kvb + o + half * 512);
        kk = p[hl]; vv = p[32 + hl];
    };

    for (int b0 = e0; b0 < e1; b0 += 64) {
        const int m = min(64, e1 - b0);
        const int my = koff[b0 + ((lane < m) ? lane : 0)];     // coalesced preload
        const int nm = (m > part) ? ((m - part + 1) >> 1) : 0; // my edges: part, part+2, ...
        uint4 kka = {}, vva = {}, kkb = {}, vvb = {};
        if (nm > 0) fetch(my, 0, kka, vva);
        if (nm > 1) fetch(my, 1, kkb, vvb);
        int t = 0;
        for (; t + 3 < nm; t += 2) {
            edge(kka, vva);
            fetch(my, t + 2, kka, vva);
            edge(kkb, vvb);
            fetch(my, t + 3, kkb, vvb);
        }
        if (t < nm)     edge(kka, vva);
        if (t + 1 < nm) edge(kkb, vvb);
        if (t + 2 < nm) { fetch(my, t + 2, kka, vva); edge(kka, vva); }
    }

    if (part == 1) {
        float* r = red[rw][lane];
        r[0] = a0; r[1] = a1; r[2] = a2; r[3] = a3;
        r[4] = a4; r[5] = a5; r[6] = a6; r[7] = a7; r[8] = wsum;
    }
    __syncthreads();
    if (part == 0) {
        const float* r = red[rw][lane];
        a0 += r[0]; a1 += r[1]; a2 += r[2]; a3 += r[3];
        a4 += r[4]; a5 += r[5]; a6 += r[6]; a7 += r[7]; wsum += r[8];
        const float inv = 1.0f / wsum;
        uint4 o;
        o.x = (unsigned)f2bf(a0 * inv) | ((unsigned)f2bf(a1 * inv) << 16);
        o.y = (unsigned)f2bf(a2 * inv) | ((unsigned)f2bf(a3 * inv) << 16);
        o.z = (unsigned)f2bf(a4 * inv) | ((unsigned)f2bf(a5 * inv) << 16);
        o.w = (unsigned)f2bf(a6 * inv) | ((unsigned)f2bf(a7 * inv) << 16);
        *((uint4*)(attnb + (size_t)(s * 2 + half) * C_) + hl) = o;
    }
}

// ---------------- K5: output projection (128x64 tiles -> 256 blocks) ----------------

__global__ __launch_bounds__(256) void gemm_proj(
        const unsigned short* __restrict__ attnb, const unsigned short* __restrict__ Wxb,
        const float* __restrict__ bx, float* __restrict__ out) {
    gemm_body<64, false>(attnb, Wxb, bx, nullptr, out, 0, 0, blockIdx.x * 128, blockIdx.y * 64);
}

// ---------------- launch ----------------

extern "C" void kernel_launch(void* const* d_in, const int* in_sizes, int n_in,
                              void* d_out, int out_size, void* d_ws, size_t ws_size,
                              hipStream_t stream) {
    const float* x  = (const float*)d_in[0];
    const int* q_id = (const int*)d_in[1];
    const int* k_id = (const int*)d_in[2];
    const float* Wq = (const float*)d_in[3];
    const float* bq = (const float*)d_in[4];
    const float* Wk = (const float*)d_in[5];
    const float* bk = (const float*)d_in[6];
    const float* Wv = (const float*)d_in[7];
    const float* bv = (const float*)d_in[8];
    const float* Wx = (const float*)d_in[9];
    const float* bx = (const float*)d_in[10];
    float* out = (float*)d_out;

    char* ws = (char*)d_ws;
    unsigned short* xb    = (unsigned short*)ws;                 ws += (size_t)MR * C_ * 2;
    unsigned short* qb    = (unsigned short*)ws;                 ws += (size_t)MR * C_ * 2;
    unsigned short* kvb   = (unsigned short*)ws;                 ws += (size_t)MR * 512 * 2;
    unsigned short* attnb = (unsigned short*)ws;                 ws += (size_t)MR * C_ * 2;
    unsigned short* Wb    = (unsigned short*)ws;                 ws += (size_t)4 * C_ * C_ * 2;
    int* count       = (int*)ws;                                 ws += S_ * 4;
    int* base        = (int*)ws;                                 ws += (S_ + 1) * 4;
    int* cursor      = (int*)ws;                                 ws += S_ * 4;
    int* koff_sorted = (int*)ws;

    hipMemsetAsync(count, 0, S_ * sizeof(int), stream);
    prep_kernel<<<1664, 256, 0, stream>>>(q_id, count, x, xb, Wq, Wk, Wv, Wx, Wb);
    scan_kernel<<<1, 1024, 0, stream>>>(count, base, cursor);
    scatter_qkv_kernel<<<896, 256, 0, stream>>>(q_id, k_id, cursor, koff_sorted,
                                                xb, Wb, bq, bk, bv, qb, kvb);
    attn_edge<<<S_ / 2, 256, 0, stream>>>(qb, kvb, base, koff_sorted, attnb);
    gemm_proj<<<dim3(MR / 128, C_ / 64), 256, 0, stream>>>(
        attnb, Wb + (size_t)3 * C_ * C_, bx, out);
}

// Round 6
// 147.101 us; speedup vs baseline: 1.5811x; 1.0568x over previous
//
#include <hip/hip_runtime.h>

// Problem constants (fixed by the dataset)
constexpr int S_  = 4096;
constexpr int B_  = 2;
constexpr int C_  = 256;
constexpr int H_  = 8;
constexpr int E_  = 131072;
constexpr int CC_ = 32;
constexpr int MR  = S_ * B_;   // 8192 rows for all GEMMs

typedef __attribute__((ext_vector_type(8))) short bf16x8_t;
typedef __attribute__((ext_vector_type(4))) float f32x4_t;

__device__ __forceinline__ unsigned short f2bf(float f) {
    unsigned int u = __float_as_uint(f);
    u += 0x7fffu + ((u >> 16) & 1u);   // round-to-nearest-even
    return (unsigned short)(u >> 16);
}
__device__ __forceinline__ float bflo(unsigned int u) { return __uint_as_float(u << 16); }
__device__ __forceinline__ float bfhi(unsigned int u) { return __uint_as_float(u & 0xffff0000u); }

__device__ __forceinline__ void cast8(const float* __restrict__ src, unsigned short* __restrict__ dst, int i) {
    const float4* s = (const float4*)src + (size_t)i * 2;
    float4 a = s[0], b = s[1];
    uint4 o;
    o.x = (unsigned)f2bf(a.x) | ((unsigned)f2bf(a.y) << 16);
    o.y = (unsigned)f2bf(a.z) | ((unsigned)f2bf(a.w) << 16);
    o.z = (unsigned)f2bf(b.x) | ((unsigned)f2bf(b.y) << 16);
    o.w = (unsigned)f2bf(b.z) | ((unsigned)f2bf(b.w) << 16);
    *((uint4*)dst + i) = o;
}

// ---------------- K1: histogram + casts ----------------
// blocks [0,512): hist; [512,1536): cast x; [1536,1664): cast W (4 matrices)

__global__ __launch_bounds__(256) void prep_kernel(
        const int* __restrict__ q_id, int* __restrict__ count,
        const float* __restrict__ x, unsigned short* __restrict__ xb,
        const float* __restrict__ Wq, const float* __restrict__ Wk,
        const float* __restrict__ Wv, const float* __restrict__ Wx,
        unsigned short* __restrict__ Wb) {
    const int bid = blockIdx.x, tid = threadIdx.x;
    if (bid < 512) {
        atomicAdd(&count[q_id[bid * 256 + tid]], 1);
    } else if (bid < 1536) {
        cast8(x, xb, (bid - 512) * 256 + tid);
    } else {
        int idx = bid - 1536;
        int z = idx >> 5;
        const float* src = (z == 0) ? Wq : (z == 1) ? Wk : (z == 2) ? Wv : Wx;
        cast8(src, Wb + (size_t)z * (C_ * C_), (idx & 31) * 256 + tid);
    }
}

// ---------------- K2: scan ----------------

__global__ __launch_bounds__(1024) void scan_kernel(const int* __restrict__ count,
                                                    int* __restrict__ base,
                                                    int* __restrict__ cursor) {
    __shared__ int wsums[16];
    const int t = threadIdx.x, lane = t & 63, w = t >> 6;
    int c0 = count[4 * t + 0], c1 = count[4 * t + 1];
    int c2 = count[4 * t + 2], c3 = count[4 * t + 3];
    int tsum = c0 + c1 + c2 + c3;
    int x = tsum;
#pragma unroll
    for (int off = 1; off < 64; off <<= 1) {
        int y = __shfl_up(x, off);
        if (lane >= off) x += y;
    }
    if (lane == 63) wsums[w] = x;
    __syncthreads();
    if (t == 0) {
        int run = 0;
#pragma unroll
        for (int i = 0; i < 16; ++i) { int v = wsums[i]; wsums[i] = run; run += v; }
        base[S_] = run;
    }
    __syncthreads();
    int excl = x - tsum + wsums[w];
    int b0 = excl, b1 = b0 + c0, b2 = b1 + c1, b3 = b2 + c2;
    base[4 * t + 0] = b0; base[4 * t + 1] = b1;
    base[4 * t + 2] = b2; base[4 * t + 3] = b3;
    cursor[4 * t + 0] = b0; cursor[4 * t + 1] = b1;
    cursor[4 * t + 2] = b2; cursor[4 * t + 3] = b3;
}

// ---------------- K3: scatter + QKV GEMM (weights-in-registers) ----------------
// blocks [0,512): scatter. blocks [512,1028): gemm — 12 n-blocks (64 cols of
// N=768 across q,k,v) x 43 m-groups. Per wave: B-strip 16x256 in 32 VGPRs,
// A staged 64 rows x K=256 in LDS, C/D frags stored directly (no LDS epilogue).

__global__ __launch_bounds__(256) void scatter_qkv_kernel(
        const int* __restrict__ q_id, const int* __restrict__ k_id,
        int* __restrict__ cursor, int* __restrict__ koff_sorted,
        const unsigned short* __restrict__ xb, const unsigned short* __restrict__ Wb,
        const float* __restrict__ bq, const float* __restrict__ bk, const float* __restrict__ bv,
        unsigned short* __restrict__ qb, unsigned short* __restrict__ kvb) {
    __shared__ __align__(16) unsigned short As[64][264];   // 33 KB, +8 pad
    const int bid = blockIdx.x, tid = threadIdx.x;
    if (bid < 512) {
        int e = bid * 256 + tid;
        int pos = atomicAdd(&cursor[q_id[e]], 1);
        koff_sorted[pos] = k_id[e] << 10;          // element offset into kvb
        return;
    }
    const int u = bid - 512;                       // 0..515
    const int nb = u % 12, mg = u / 12;            // n-block, m-group (0..42)
    const int lane = tid & 63, wave = tid >> 6;
    const int l16 = lane & 15, quad = lane >> 4;
    const int z = nb >> 2;                         // 0=q 1=k 2=v
    const int colz = ((nb & 3) << 6) + (wave << 4);

    // B-strip: W rows [colz, colz+16), full K, in registers
    const unsigned short* Wrow = Wb + (size_t)z * (C_ * C_) + (size_t)(colz + l16) * C_;
    bf16x8_t breg[8];
#pragma unroll
    for (int ks = 0; ks < 8; ++ks)
        breg[ks] = *(const bf16x8_t*)(Wrow + ks * 32 + quad * 8);

    const float* bias = (z == 0) ? bq : (z == 1) ? bk : bv;
    const float bcol = bias[colz + l16];
    unsigned short* ob = (z == 0) ? qb : kvb;
    const int ostr = (z == 0) ? 256 : 512;
    const int ocol = ((z == 2) ? 256 : 0) + colz + l16;

    const int c0 = (mg * 128) / 43, c1 = ((mg + 1) * 128) / 43;
    for (int c = c0; c < c1; ++c) {
        const int mbase = c * 64;
        __syncthreads();
#pragma unroll
        for (int it = 0; it < 8; ++it) {
            int l = it * 256 + tid;
            int r = l >> 5, cc = (l & 31) << 3;
            *(uint4*)&As[r][cc] = *(const uint4*)&xb[(size_t)(mbase + r) * C_ + cc];
        }
        __syncthreads();
#pragma unroll
        for (int mt = 0; mt < 4; ++mt) {
            f32x4_t acc = {0.f, 0.f, 0.f, 0.f};
#pragma unroll
            for (int ks = 0; ks < 8; ++ks) {
                bf16x8_t a = *(const bf16x8_t*)&As[mt * 16 + l16][ks * 32 + quad * 8];
                acc = __builtin_amdgcn_mfma_f32_16x16x32_bf16(a, breg[ks], acc, 0, 0, 0);
            }
            const int row0 = mbase + mt * 16 + quad * 4;
#pragma unroll
            for (int r = 0; r < 4; ++r)
                ob[(size_t)(row0 + r) * ostr + ocol] = f2bf(acc[r] + bcol);
        }
    }
}

// ---------------- K4: edge attention (R5 pipelined version, unchanged) ----------------

__global__ __launch_bounds__(256) void attn_edge(
        const unsigned short* __restrict__ qb, const unsigned short* __restrict__ kvb,
        const int* __restrict__ base, const int* __restrict__ koff,
        unsigned short* __restrict__ attnb) {
    __shared__ float red[2][64][9];
    const int lane = threadIdx.x & 63;
    const int wave = threadIdx.x >> 6;
    const int rw = wave >> 1, part = wave & 1;
    const int s = blockIdx.x * 2 + rw;
    const int half = lane >> 5, hl = lane & 31;
    const int e0 = __builtin_amdgcn_readfirstlane(base[s]);
    const int e1 = __builtin_amdgcn_readfirstlane(base[s + 1]);

    const uint4 qq = *((const uint4*)(qb + (size_t)(s * 2 + half) * C_) + hl);
    const float q0 = bflo(qq.x), q1 = bfhi(qq.x), q2 = bflo(qq.y), q3 = bfhi(qq.y);
    const float q4 = bflo(qq.z), q5 = bfhi(qq.z), q6 = bflo(qq.w), q7 = bfhi(qq.w);

    float a0 = 0.f, a1 = 0.f, a2 = 0.f, a3 = 0.f, a4 = 0.f, a5 = 0.f, a6 = 0.f, a7 = 0.f;
    float wsum = 0.f;
    const float scale = 0.17677669529663687f;   // 1/sqrt(32)

    auto edge = [&](const uint4& kk, const uint4& vv) {
        float p = q0 * bflo(kk.x) + q1 * bfhi(kk.x)
                + q2 * bflo(kk.y) + q3 * bfhi(kk.y)
                + q4 * bflo(kk.z) + q5 * bfhi(kk.z)
                + q6 * bflo(kk.w) + q7 * bfhi(kk.w);
        p += __shfl_xor(p, 1);
        p += __shfl_xor(p, 2);
        const float w = __expf(p * scale);
        a0 = fmaf(w, bflo(vv.x), a0); a1 = fmaf(w, bfhi(vv.x), a1);
        a2 = fmaf(w, bflo(vv.y), a2); a3 = fmaf(w, bfhi(vv.y), a3);
        a4 = fmaf(w, bflo(vv.z), a4); a5 = fmaf(w, bfhi(vv.z), a5);
        a6 = fmaf(w, bflo(vv.w), a6); a7 = fmaf(w, bfhi(vv.w), a7);
        wsum += w;
    };
    auto fetch = [&](int my, int t, uint4& kk, uint4& vv) {
        int o = __builtin_amdgcn_readlane(my, part + 2 * t);
        const uint4* p = (const uint4*)(kvb + o + half * 512);
        kk = p[hl]; vv = p[32 + hl];
    };

    for (int b0 = e0; b0 < e1; b0 += 64) {
        const int m = min(64, e1 - b0);
        const int my = koff[b0 + ((lane < m) ? lane : 0)];
        const int nm = (m > part) ? ((m - part + 1) >> 1) : 0;
        uint4 kka = {}, vva = {}, kkb = {}, vvb = {};
        if (nm > 0) fetch(my, 0, kka, vva);
        if (nm > 1) fetch(my, 1, kkb, vvb);
        int t = 0;
        for (; t + 3 < nm; t += 2) {
            edge(kka, vva);
            fetch(my, t + 2, kka, vva);
            edge(kkb, vvb);
            fetch(my, t + 3, kkb, vvb);
        }
        if (t < nm)     edge(kka, vva);
        if (t + 1 < nm) edge(kkb, vvb);
        if (t + 2 < nm) { fetch(my, t + 2, kka, vva); edge(kka, vva); }
    }

    if (part == 1) {
        float* r = red[rw][lane];
        r[0] = a0; r[1] = a1; r[2] = a2; r[3] = a3;
        r[4] = a4; r[5] = a5; r[6] = a6; r[7] = a7; r[8] = wsum;
    }
    __syncthreads();
    if (part == 0) {
        const float* r = red[rw][lane];
        a0 += r[0]; a1 += r[1]; a2 += r[2]; a3 += r[3];
        a4 += r[4]; a5 += r[5]; a6 += r[6]; a7 += r[7]; wsum += r[8];
        const float inv = 1.0f / wsum;
        uint4 o;
        o.x = (unsigned)f2bf(a0 * inv) | ((unsigned)f2bf(a1 * inv) << 16);
        o.y = (unsigned)f2bf(a2 * inv) | ((unsigned)f2bf(a3 * inv) << 16);
        o.z = (unsigned)f2bf(a4 * inv) | ((unsigned)f2bf(a5 * inv) << 16);
        o.w = (unsigned)f2bf(a6 * inv) | ((unsigned)f2bf(a7 * inv) << 16);
        *((uint4*)(attnb + (size_t)(s * 2 + half) * C_) + hl) = o;
    }
}

// ---------------- K5: output projection (weights-in-registers) ----------------
// 512 blocks = 4 n-blocks x 128 m-groups (one 64-row chunk each). fp32 out.

__global__ __launch_bounds__(256) void gemm_proj(
        const unsigned short* __restrict__ attnb, const unsigned short* __restrict__ Wxb,
        const float* __restrict__ bx, float* __restrict__ out) {
    __shared__ __align__(16) unsigned short As[64][264];
    const int tid = threadIdx.x;
    const int nb = blockIdx.x & 3, mg = blockIdx.x >> 2;
    const int lane = tid & 63, wave = tid >> 6;
    const int l16 = lane & 15, quad = lane >> 4;
    const int colz = (nb << 6) + (wave << 4);

    const unsigned short* Wrow = Wxb + (size_t)(colz + l16) * C_;
    bf16x8_t breg[8];
#pragma unroll
    for (int ks = 0; ks < 8; ++ks)
        breg[ks] = *(const bf16x8_t*)(Wrow + ks * 32 + quad * 8);
    const float bcol = bx[colz + l16];
    const int ocol = colz + l16;

    const int mbase = mg * 64;
#pragma unroll
    for (int it = 0; it < 8; ++it) {
        int l = it * 256 + tid;
        int r = l >> 5, cc = (l & 31) << 3;
        *(uint4*)&As[r][cc] = *(const uint4*)&attnb[(size_t)(mbase + r) * C_ + cc];
    }
    __syncthreads();
#pragma unroll
    for (int mt = 0; mt < 4; ++mt) {
        f32x4_t acc = {0.f, 0.f, 0.f, 0.f};
#pragma unroll
        for (int ks = 0; ks < 8; ++ks) {
            bf16x8_t a = *(const bf16x8_t*)&As[mt * 16 + l16][ks * 32 + quad * 8];
            acc = __builtin_amdgcn_mfma_f32_16x16x32_bf16(a, breg[ks], acc, 0, 0, 0);
        }
        const int row0 = mbase + mt * 16 + quad * 4;
#pragma unroll
        for (int r = 0; r < 4; ++r)
            out[(size_t)(row0 + r) * C_ + ocol] = acc[r] + bcol;
    }
}

// ---------------- launch ----------------

extern "C" void kernel_launch(void* const* d_in, const int* in_sizes, int n_in,
                              void* d_out, int out_size, void* d_ws, size_t ws_size,
                              hipStream_t stream) {
    const float* x  = (const float*)d_in[0];
    const int* q_id = (const int*)d_in[1];
    const int* k_id = (const int*)d_in[2];
    const float* Wq = (const float*)d_in[3];
    const float* bq = (const float*)d_in[4];
    const float* Wk = (const float*)d_in[5];
    const float* bk = (const float*)d_in[6];
    const float* Wv = (const float*)d_in[7];
    const float* bv = (const float*)d_in[8];
    const float* Wx = (const float*)d_in[9];
    const float* bx = (const float*)d_in[10];
    float* out = (float*)d_out;

    char* ws = (char*)d_ws;
    unsigned short* xb    = (unsigned short*)ws;                 ws += (size_t)MR * C_ * 2;
    unsigned short* qb    = (unsigned short*)ws;                 ws += (size_t)MR * C_ * 2;
    unsigned short* kvb   = (unsigned short*)ws;                 ws += (size_t)MR * 512 * 2;
    unsigned short* attnb = (unsigned short*)ws;                 ws += (size_t)MR * C_ * 2;
    unsigned short* Wb    = (unsigned short*)ws;                 ws += (size_t)4 * C_ * C_ * 2;
    int* count       = (int*)ws;                                 ws += S_ * 4;
    int* base        = (int*)ws;                                 ws += (S_ + 1) * 4;
    int* cursor      = (int*)ws;                                 ws += S_ * 4;
    int* koff_sorted = (int*)ws;

    hipMemsetAsync(count, 0, S_ * sizeof(int), stream);
    prep_kernel<<<1664, 256, 0, stream>>>(q_id, count, x, xb, Wq, Wk, Wv, Wx, Wb);
    scan_kernel<<<1, 1024, 0, stream>>>(count, base, cursor);
    scatter_qkv_kernel<<<1028, 256, 0, stream>>>(q_id, k_id, cursor, koff_sorted,
                                                 xb, Wb, bq, bk, bv, qb, kvb);
    attn_edge<<<S_ / 2, 256, 0, stream>>>(qb, kvb, base, koff_sorted, attnb);
    gemm_proj<<<512, 256, 0, stream>>>(attnb, Wb + (size_t)3 * C_ * C_, bx, out);
}